// Round 18
// baseline (51450.787 us; speedup 1.0000x reference)
//
#include <hip/hip_runtime.h>
#include <stdint.h>

#define T_STEPS 25
#define BATCH   1024
#define IN_F    784
#define HID     4096
#define OUTF    10
// Eigen SINGLE-THREADED gebp blocking (verified bit-exact R11-R17):
// max_kc=288 evened -> kc(784)=264 (264+264+256), kc(4096)=280 (14x280+176).
#define KC_L0   264
#define KC_L1   280
#define KCHUNK  128

typedef float v2f __attribute__((ext_vector_type(2)));

// ---------------- Threefry-2x32, key = (0, 42), 20 rounds ----------------
__device__ __forceinline__ uint32_t rotl32(uint32_t x, int d) {
    return (x << d) | (x >> (32 - d));
}

__device__ __forceinline__ void threefry2x32_42(uint32_t x0, uint32_t x1,
                                                uint32_t& r0, uint32_t& r1) {
    const uint32_t k0 = 0u, k1 = 42u;
    const uint32_t k2 = k0 ^ k1 ^ 0x1BD11BDAu;
    x0 += k0; x1 += k1;
#define TF_ROUND(r) { x0 += x1; x1 = rotl32(x1, r); x1 ^= x0; }
    TF_ROUND(13) TF_ROUND(15) TF_ROUND(26) TF_ROUND(6)
    x0 += k1; x1 += k2 + 1u;
    TF_ROUND(17) TF_ROUND(29) TF_ROUND(16) TF_ROUND(24)
    x0 += k2; x1 += k0 + 2u;
    TF_ROUND(13) TF_ROUND(15) TF_ROUND(26) TF_ROUND(6)
    x0 += k0; x1 += k1 + 3u;
    TF_ROUND(17) TF_ROUND(29) TF_ROUND(16) TF_ROUND(24)
    x0 += k1; x1 += k2 + 4u;
    TF_ROUND(13) TF_ROUND(15) TF_ROUND(26) TF_ROUND(6)
    x0 += k2; x1 += k0 + 5u;
#undef TF_ROUND
    r0 = x0; r1 = x1;
}

// ---------------- Input spike generation (bitmask, ballot) ----------------
__global__ __launch_bounds__(256) void gen_spikes(const float* __restrict__ x,
                                                  uint64_t* __restrict__ Sin) {
    const int lane = threadIdx.x & 63;
    const int wid  = __builtin_amdgcn_readfirstlane(blockIdx.x * 4 + (threadIdx.x >> 6));
    if (wid >= T_STEPS * BATCH) return;
    const int b = wid % BATCH;

    for (int qw = 0; qw < 16; ++qw) {
        bool pred = false;
        const int f = qw * 64 + lane;
        if (f < IN_F) {
            const uint32_t i = (uint32_t)(wid * IN_F + f);
            uint32_t r0, r1;
            threefry2x32_42(0u, i, r0, r1);
            const uint32_t bits = r0 ^ r1;
            const uint32_t fbits = (bits >> 9) | 0x3f800000u;
            const float u = __uint_as_float(fbits) - 1.0f;
            float p = x[b * IN_F + f];
            p = fminf(fmaxf(p, 0.0f), 1.0f);
            pred = (u < p);
        }
        const uint64_t mask = __ballot((int)pred);
        if (lane == 0) Sin[(long long)wid * 16 + qw] = mask;
    }
}

// ---------------- Weight transpose: WT[f*H + h] = W[h*F + f] ----------------
__global__ __launch_bounds__(256) void transpose_w(const float* __restrict__ W,
                                                   float* __restrict__ WT,
                                                   int H, int F) {
    const long long idx = (long long)blockIdx.x * blockDim.x + threadIdx.x;
    const long long tot = (long long)H * F;
    if (idx >= tot) return;
    const long long f = idx / H;
    const long long h = idx % H;
    WT[idx] = W[h * (long long)F + f];
}

// ---------------- Fused layer: t-split 2-wave blocks, 64 cols -------------
// Bit-exact to Eigen gebp (verified): S[t] = fmaf(fbit, w, S[t]) per k
// ascending, folds at global k % KCB == 0 via scalar countdown, tail fold,
// strict-f32 LIF. R18 structure: block = 128 thr = 2 waves, ONE b, 64 cols
// (col = hb*64+lane); wave0 owns t0..11, wave1 owns t12..24 (per-t chains
// independent -> identical arithmetic). Active weight slab per hb = 1 MB;
// co-resident span ~2.75 MB < 4 MB per-XCD L2. LIF via LDS handoff.
template<int KCB, int KTOT, int IN_STRIDE, int HTOT>
__global__ __launch_bounds__(128, 4) void layer_fmac(
    const uint64_t* __restrict__ Bin,   // [T][B][IN_STRIDE] u64, bit index = k
    const float*    __restrict__ WT,    // [KTOT][HTOT]
    uint64_t*       __restrict__ Bout)  // [T][B][HTOT/64]
{
    __shared__ alignas(16) float tile[KCHUNK * 28];  // 14 KB
    const int tid  = threadIdx.x;
    const int lane = tid & 63;
    const int wv   = tid >> 6;                       // 0: t0..11, 1: t12..24
    const int b    = blockIdx.x % BATCH;             // hb-major grid
    const int hb   = blockIdx.x / BATCH;
    const int col  = hb * 64 + lane;

    v2f S[6], A[6];
    float S1x = 0.0f, A1x = 0.0f;                    // t24 (wave1 only)
#pragma unroll
    for (int j = 0; j < 6; ++j) { S[j] = (v2f)0.0f; A[j] = (v2f)0.0f; }

    int nf = KCB;                       // next fold boundary (k+1 == nf)
    const int NCH = (KTOT + KCHUNK - 1) / KCHUNK;
    for (int c = 0; c < NCH; ++c) {
        const int k0 = c * KCHUNK;
        const int kv = (KTOT - k0 < KCHUNK) ? (KTOT - k0) : KCHUNK;
        __syncthreads();                // previous tile fully consumed
        const int NV = kv * T_STEPS;
        for (int r = 0; r < (NV + 127) / 128; ++r) {
            const int idx = r * 128 + tid;
            if (idx < NV) {
                const int kk = (idx * 5243) >> 17;   // idx/25, exact < 43690
                const int t  = idx - kk * 25;
                const int k  = k0 + kk;
                const uint64_t word =
                    Bin[((long long)t * BATCH + b) * IN_STRIDE + (k >> 6)];
                tile[kk * 28 + t] = ((word >> (k & 63)) & 1ull) ? 1.0f : 0.0f;
            }
        }
        __syncthreads();

        float w = WT[(long long)k0 * HTOT + col];
        for (int kk = 0; kk < kv; ++kk) {
            const int kn = (kk + 1 < kv) ? kk + 1 : kv - 1;   // clamped prefetch
            const float wn = WT[(long long)(k0 + kn) * HTOT + col];
            const float* fb = &tile[kk * 28] + wv * 12;       // 16B aligned
            v2f w2; w2.x = w; w2.y = w;
            const float4 f0 = *(const float4*)(fb);
            const float4 f1 = *(const float4*)(fb + 4);
            const float4 f2 = *(const float4*)(fb + 8);
            v2f p0; p0.x = f0.x; p0.y = f0.y;
            v2f p1; p1.x = f0.z; p1.y = f0.w;
            v2f p2; p2.x = f1.x; p2.y = f1.y;
            v2f p3; p3.x = f1.z; p3.y = f1.w;
            v2f p4; p4.x = f2.x; p4.y = f2.y;
            v2f p5; p5.x = f2.z; p5.y = f2.w;
            S[0] = __builtin_elementwise_fma(p0, w2, S[0]);
            S[1] = __builtin_elementwise_fma(p1, w2, S[1]);
            S[2] = __builtin_elementwise_fma(p2, w2, S[2]);
            S[3] = __builtin_elementwise_fma(p3, w2, S[3]);
            S[4] = __builtin_elementwise_fma(p4, w2, S[4]);
            S[5] = __builtin_elementwise_fma(p5, w2, S[5]);
            if (wv) S1x = fmaf(tile[kk * 28 + 24], w, S1x);   // t24
            if (k0 + kk + 1 == nf) {                // exact KC fold boundary
#pragma unroll
                for (int j = 0; j < 6; ++j) { A[j] = A[j] + S[j]; S[j] = (v2f)0.0f; }
                if (wv) { A1x = __fadd_rn(A1x, S1x); S1x = 0.0f; }
                nf += KCB;
            }
            w = wn;
        }
    }
    if (KTOT % KCB != 0) {
#pragma unroll
        for (int j = 0; j < 6; ++j) A[j] = A[j] + S[j];
        if (wv) A1x = __fadd_rn(A1x, S1x);
    }

    // ---- LIF handoff: stage A[t] in LDS (reuse tile), wave0 runs LIF ----
    __syncthreads();                    // all sweeping done before reuse
    float* Abuf = tile;                 // [25][64]
#pragma unroll
    for (int j = 0; j < 6; ++j) {
        const int t0 = wv * 12 + 2 * j;
        Abuf[t0 * 64 + lane]       = A[j].x;
        Abuf[(t0 + 1) * 64 + lane] = A[j].y;
    }
    if (wv) Abuf[24 * 64 + lane] = A1x;
    __syncthreads();

    if (wv == 0) {
        float m = 0.0f;
        for (int t = 0; t < T_STEPS; ++t) {
            const float ca = Abuf[t * 64 + lane];
            const float reset = (m > 1.0f) ? 1.0f : 0.0f;
            m = __fsub_rn(__fadd_rn(__fmul_rn(0.9f, m), ca), reset);
            const uint64_t mask = __ballot((int)(m > 1.0f));
            if (lane == 0)
                Bout[((long long)t * BATCH + b) * (HTOT / 64) + hb] = mask;
        }
    }
}

// ---------------- Output layer (H=10): counts, blocked f32 (kc=280) -------
__global__ __launch_bounds__(256) void layer_out(const uint64_t* __restrict__ S1,
                                                 const float* __restrict__ W2,
                                                 float* __restrict__ out) {
    const int idx = blockIdx.x * blockDim.x + threadIdx.x;
    const int b = idx >> 4;   // 16 threads per batch row (10 used)
    const int o = idx & 15;
    if (b >= BATCH) return;

    float m = 0.0f;
    float cnt = 0.0f;
    for (int t = 0; t < T_STEPS; ++t) {
        float acc = 0.0f;
        float S = 0.0f;
        if (o < OUTF) {
            for (int qw = 0; qw < 64; ++qw) {
                const uint64_t sw = S1[((long long)t * BATCH + b) * 64 + qw];
                const float* wrow = W2 + (long long)o * HID + qw * 64;
#pragma unroll
                for (int fb = 0; fb < 64; ++fb) {
                    S = __fadd_rn(S, ((sw >> fb) & 1ull) ? wrow[fb] : 0.0f);
                    if (((qw * 64 + fb + 1) % KC_L1) == 0) {
                        acc = __fadd_rn(acc, S);
                        S = 0.0f;
                    }
                }
            }
            if (HID % KC_L1 != 0) acc = __fadd_rn(acc, S);
        }
        const float reset = (m > 1.0f) ? 1.0f : 0.0f;
        m = __fsub_rn(__fadd_rn(__fmul_rn(0.9f, m), acc), reset);
        if (m > 1.0f) cnt += 1.0f;
    }
    if (o < OUTF) out[b * OUTF + o] = cnt;
}

// ---------------- Launch ----------------
extern "C" void kernel_launch(void* const* d_in, const int* in_sizes, int n_in,
                              void* d_out, int out_size, void* d_ws, size_t ws_size,
                              hipStream_t stream) {
    const float* x  = (const float*)d_in[0];
    const float* W0 = (const float*)d_in[1];
    const float* W1 = (const float*)d_in[2];
    const float* W2 = (const float*)d_in[3];
    float* out = (float*)d_out;

    char* ws = (char*)d_ws;
    size_t off = 0;
    float* WT0 = (float*)(ws + off); off += (size_t)IN_F * HID * sizeof(float);   // 12.8 MB
    float* WT1 = (float*)(ws + off); off += (size_t)HID * HID * sizeof(float);    // 64 MB
    uint64_t* Sin = (uint64_t*)(ws + off); off += (size_t)T_STEPS * BATCH * 16 * 8; // 3.3 MB
    uint64_t* S0  = (uint64_t*)(ws + off); off += (size_t)T_STEPS * BATCH * 64 * 8; // 13.1 MB
    uint64_t* S1  = (uint64_t*)(ws + off); off += (size_t)T_STEPS * BATCH * 64 * 8; // 13.1 MB
    (void)off; (void)ws_size; (void)in_sizes; (void)n_in; (void)out_size;

    // 1) transpose weights (verified layout)
    {
        long long tot0 = (long long)HID * IN_F;
        transpose_w<<<(int)((tot0 + 255) / 256), 256, 0, stream>>>(W0, WT0, HID, IN_F);
        long long tot1 = (long long)HID * HID;
        transpose_w<<<(int)((tot1 + 255) / 256), 256, 0, stream>>>(W1, WT1, HID, HID);
    }
    // 2) Poisson spike raster via threefry (partitionable, XOR readout)
    gen_spikes<<<(T_STEPS * BATCH) / 4, 256, 0, stream>>>(x, Sin);
    // 3) layer 0: 784 -> 4096, kc=264
    layer_fmac<KC_L0, IN_F, 16, HID>
        <<<(HID / 64) * BATCH, 128, 0, stream>>>(Sin, WT0, S0);
    // 4) layer 1: 4096 -> 4096, kc=280
    layer_fmac<KC_L1, HID, 64, HID>
        <<<(HID / 64) * BATCH, 128, 0, stream>>>(S0, WT1, S1);
    // 5) layer 2: 4096 -> 10, kc=280, spike counts
    layer_out<<<BATCH * 16 / 256, 256, 0, stream>>>(S1, W2, out);
}

// Round 19
// 19607.506 us; speedup vs baseline: 2.6240x; 2.6240x over previous
//
#include <hip/hip_runtime.h>
#include <stdint.h>

#define T_STEPS 25
#define BATCH   1024
#define IN_F    784
#define HID     4096
#define OUTF    10
// Eigen SINGLE-THREADED gebp blocking (verified bit-exact R11-R18):
// max_kc=288 evened -> kc(784)=264 (264+264+256), kc(4096)=280 (14x280+176).
#define KC_L0   264
#define KC_L1   280
#define KCHUNK  128
#define COLS    512     // columns per hb slab (per block)

typedef float v2f __attribute__((ext_vector_type(2)));

// ---------------- Threefry-2x32, key = (0, 42), 20 rounds ----------------
__device__ __forceinline__ uint32_t rotl32(uint32_t x, int d) {
    return (x << d) | (x >> (32 - d));
}

__device__ __forceinline__ void threefry2x32_42(uint32_t x0, uint32_t x1,
                                                uint32_t& r0, uint32_t& r1) {
    const uint32_t k0 = 0u, k1 = 42u;
    const uint32_t k2 = k0 ^ k1 ^ 0x1BD11BDAu;
    x0 += k0; x1 += k1;
#define TF_ROUND(r) { x0 += x1; x1 = rotl32(x1, r); x1 ^= x0; }
    TF_ROUND(13) TF_ROUND(15) TF_ROUND(26) TF_ROUND(6)
    x0 += k1; x1 += k2 + 1u;
    TF_ROUND(17) TF_ROUND(29) TF_ROUND(16) TF_ROUND(24)
    x0 += k2; x1 += k0 + 2u;
    TF_ROUND(13) TF_ROUND(15) TF_ROUND(26) TF_ROUND(6)
    x0 += k0; x1 += k1 + 3u;
    TF_ROUND(17) TF_ROUND(29) TF_ROUND(16) TF_ROUND(24)
    x0 += k1; x1 += k2 + 4u;
    TF_ROUND(13) TF_ROUND(15) TF_ROUND(26) TF_ROUND(6)
    x0 += k2; x1 += k0 + 5u;
#undef TF_ROUND
    r0 = x0; r1 = x1;
}

// ---------------- Input spike generation (bitmask, ballot) ----------------
__global__ __launch_bounds__(256) void gen_spikes(const float* __restrict__ x,
                                                  uint64_t* __restrict__ Sin) {
    const int lane = threadIdx.x & 63;
    const int wid  = __builtin_amdgcn_readfirstlane(blockIdx.x * 4 + (threadIdx.x >> 6));
    if (wid >= T_STEPS * BATCH) return;
    const int b = wid % BATCH;

    for (int qw = 0; qw < 16; ++qw) {
        bool pred = false;
        const int f = qw * 64 + lane;
        if (f < IN_F) {
            const uint32_t i = (uint32_t)(wid * IN_F + f);
            uint32_t r0, r1;
            threefry2x32_42(0u, i, r0, r1);
            const uint32_t bits = r0 ^ r1;
            const uint32_t fbits = (bits >> 9) | 0x3f800000u;
            const float u = __uint_as_float(fbits) - 1.0f;
            float p = x[b * IN_F + f];
            p = fminf(fmaxf(p, 0.0f), 1.0f);
            pred = (u < p);
        }
        const uint64_t mask = __ballot((int)pred);
        if (lane == 0) Sin[(long long)wid * 16 + qw] = mask;
    }
}

// ------- Weight transpose+slab-pack: WTp[hb][f][c] = W[hb*512+c][f] -------
// Each output element written exactly once; kernel reads WTp[(hb*K+f)*512+c]
// which equals the old WT[f*H + (hb*512+c)] value — bit-identical operands,
// but each hb's slab is now CONTIGUOUS (no 16KB k-stride -> no L2 set alias).
__global__ __launch_bounds__(256) void transpose_pack(const float* __restrict__ W,
                                                      float* __restrict__ WTp,
                                                      int H, int F) {
    const long long idx = (long long)blockIdx.x * blockDim.x + threadIdx.x;
    const long long tot = (long long)H * F;
    if (idx >= tot) return;
    const long long f = idx / H;
    const long long h = idx % H;
    const long long hb = h >> 9;          // h / 512
    const long long c  = h & 511;         // h % 512
    WTp[(hb * F + f) * COLS + c] = W[h * (long long)F + f];
}

// ---------------- Fused layer: 2 h-cols/thread, packed-f32 MACs -----------
// R17-verbatim arithmetic (bit-exact, verified): S += fbit*w per k ascending,
// folds at global k % KCB == 0 via scalar countdown, tail fold, strict LIF.
// R19 change: weights read from hb-contiguous slab WTp[hb][k][512].
template<int KCB, int KTOT, int IN_STRIDE, int HTOT, int WPB>
__global__ __launch_bounds__(WPB * 64, 4) void layer_fmac(
    const uint64_t* __restrict__ Bin,   // [T][B][IN_STRIDE] u64, bit index = k
    const float*    __restrict__ WTp,   // [H/512][KTOT][512] packed slabs
    uint64_t*       __restrict__ Bout)  // [T][B][HTOT/64]
{
    __shared__ alignas(16) float tile[KCHUNK * 28];  // 14 KB
    const int tid  = threadIdx.x;
    const int lane = tid & 63;
    const int wv   = tid >> 6;
    const int b    = blockIdx.x % BATCH;             // hb-major grid
    const int hb   = blockIdx.x / BATCH;
    const int ca   = wv * 128 + lane;                // col within slab
    const int cc   = ca + 64;
    const float* __restrict__ Wslab = WTp + (long long)hb * KTOT * COLS;

    v2f  SA[12], SB[12], AA[12], AB[12];
    float SA24, SB24, AA24, AB24;
#pragma unroll
    for (int j = 0; j < 12; ++j) {
        SA[j] = (v2f)0.0f; SB[j] = (v2f)0.0f;
        AA[j] = (v2f)0.0f; AB[j] = (v2f)0.0f;
    }
    SA24 = SB24 = AA24 = AB24 = 0.0f;

    int nf = KCB;                       // next fold boundary (k+1 == nf)
    const int NCH = (KTOT + KCHUNK - 1) / KCHUNK;
    for (int c = 0; c < NCH; ++c) {
        const int k0 = c * KCHUNK;
        const int kv = (KTOT - k0 < KCHUNK) ? (KTOT - k0) : KCHUNK;
        __syncthreads();                // previous tile fully consumed
        const int NV = kv * T_STEPS;
        for (int r = 0; r < (NV + WPB * 64 - 1) / (WPB * 64); ++r) {
            const int idx = r * (WPB * 64) + tid;
            if (idx < NV) {
                const int kk = (idx * 5243) >> 17;   // idx/25, exact < 43690
                const int t  = idx - kk * 25;
                const int k  = k0 + kk;
                const uint64_t word =
                    Bin[((long long)t * BATCH + b) * IN_STRIDE + (k >> 6)];
                tile[kk * 28 + t] = ((word >> (k & 63)) & 1ull) ? 1.0f : 0.0f;
            }
        }
        __syncthreads();

        float wa = Wslab[(long long)k0 * COLS + ca];
        float wb = Wslab[(long long)k0 * COLS + cc];
        for (int kk = 0; kk < kv; ++kk) {
            const int kn = (kk + 1 < kv) ? kk + 1 : kv - 1;   // clamped prefetch
            const float wan = Wslab[(long long)(k0 + kn) * COLS + ca];
            const float wbn = Wslab[(long long)(k0 + kn) * COLS + cc];
            const float* fb = &tile[kk * 28];
            v2f wa2; wa2.x = wa; wa2.y = wa;
            v2f wb2; wb2.x = wb; wb2.y = wb;
#pragma unroll
            for (int q = 0; q < 6; ++q) {           // 6 x ds_read_b128
                const float4 f = *(const float4*)(fb + 4 * q);
                v2f plo; plo.x = f.x; plo.y = f.y;
                v2f phi; phi.x = f.z; phi.y = f.w;
                SA[2*q]   = __builtin_elementwise_fma(plo, wa2, SA[2*q]);
                SA[2*q+1] = __builtin_elementwise_fma(phi, wa2, SA[2*q+1]);
                SB[2*q]   = __builtin_elementwise_fma(plo, wb2, SB[2*q]);
                SB[2*q+1] = __builtin_elementwise_fma(phi, wb2, SB[2*q+1]);
            }
            {   const float f24 = fb[24];
                SA24 = fmaf(f24, wa, SA24);
                SB24 = fmaf(f24, wb, SB24); }
            if (k0 + kk + 1 == nf) {                // exact KC fold boundary
#pragma unroll
                for (int j = 0; j < 12; ++j) {
                    AA[j] = AA[j] + SA[j];  SA[j] = (v2f)0.0f;
                    AB[j] = AB[j] + SB[j];  SB[j] = (v2f)0.0f;
                }
                AA24 = __fadd_rn(AA24, SA24);  SA24 = 0.0f;
                AB24 = __fadd_rn(AB24, SB24);  SB24 = 0.0f;
                nf += KCB;
            }
            wa = wan; wb = wbn;
        }
    }
    if (KTOT % KCB != 0) {
#pragma unroll
        for (int j = 0; j < 12; ++j) {
            AA[j] = AA[j] + SA[j];
            AB[j] = AB[j] + SB[j];
        }
        AA24 = __fadd_rn(AA24, SA24);
        AB24 = __fadd_rn(AB24, SB24);
    }

    // LIF recursion x2, strict f32 separate roundings (verified R11)
    float ma = 0.0f, mb = 0.0f;
    const long long wbase = hb * (WPB * 2) + wv * 2;
#pragma unroll
    for (int t = 0; t < T_STEPS; ++t) {
        const float caf = (t == 24) ? AA24 : ((t & 1) ? AA[t >> 1].y : AA[t >> 1].x);
        const float cbf = (t == 24) ? AB24 : ((t & 1) ? AB[t >> 1].y : AB[t >> 1].x);
        const float ra = (ma > 1.0f) ? 1.0f : 0.0f;
        ma = __fsub_rn(__fadd_rn(__fmul_rn(0.9f, ma), caf), ra);
        const float rb = (mb > 1.0f) ? 1.0f : 0.0f;
        mb = __fsub_rn(__fadd_rn(__fmul_rn(0.9f, mb), cbf), rb);
        const uint64_t mka = __ballot((int)(ma > 1.0f));
        const uint64_t mkb = __ballot((int)(mb > 1.0f));
        if (lane == 0) {
            uint64_t* dst = &Bout[((long long)t * BATCH + b) * (HTOT / 64) + wbase];
            dst[0] = mka;
            dst[1] = mkb;
        }
    }
}

// ---------------- Output layer (H=10): counts, blocked f32 (kc=280) -------
__global__ __launch_bounds__(256) void layer_out(const uint64_t* __restrict__ S1,
                                                 const float* __restrict__ W2,
                                                 float* __restrict__ out) {
    const int idx = blockIdx.x * blockDim.x + threadIdx.x;
    const int b = idx >> 4;   // 16 threads per batch row (10 used)
    const int o = idx & 15;
    if (b >= BATCH) return;

    float m = 0.0f;
    float cnt = 0.0f;
    for (int t = 0; t < T_STEPS; ++t) {
        float acc = 0.0f;
        float S = 0.0f;
        if (o < OUTF) {
            for (int qw = 0; qw < 64; ++qw) {
                const uint64_t sw = S1[((long long)t * BATCH + b) * 64 + qw];
                const float* wrow = W2 + (long long)o * HID + qw * 64;
#pragma unroll
                for (int fb = 0; fb < 64; ++fb) {
                    S = __fadd_rn(S, ((sw >> fb) & 1ull) ? wrow[fb] : 0.0f);
                    if (((qw * 64 + fb + 1) % KC_L1) == 0) {
                        acc = __fadd_rn(acc, S);
                        S = 0.0f;
                    }
                }
            }
            if (HID % KC_L1 != 0) acc = __fadd_rn(acc, S);
        }
        const float reset = (m > 1.0f) ? 1.0f : 0.0f;
        m = __fsub_rn(__fadd_rn(__fmul_rn(0.9f, m), acc), reset);
        if (m > 1.0f) cnt += 1.0f;
    }
    if (o < OUTF) out[b * OUTF + o] = cnt;
}

// ---------------- Launch ----------------
extern "C" void kernel_launch(void* const* d_in, const int* in_sizes, int n_in,
                              void* d_out, int out_size, void* d_ws, size_t ws_size,
                              hipStream_t stream) {
    const float* x  = (const float*)d_in[0];
    const float* W0 = (const float*)d_in[1];
    const float* W1 = (const float*)d_in[2];
    const float* W2 = (const float*)d_in[3];
    float* out = (float*)d_out;

    char* ws = (char*)d_ws;
    size_t off = 0;
    float* WT0 = (float*)(ws + off); off += (size_t)IN_F * HID * sizeof(float);   // 12.8 MB
    float* WT1 = (float*)(ws + off); off += (size_t)HID * HID * sizeof(float);    // 64 MB
    uint64_t* Sin = (uint64_t*)(ws + off); off += (size_t)T_STEPS * BATCH * 16 * 8; // 3.3 MB
    uint64_t* S0  = (uint64_t*)(ws + off); off += (size_t)T_STEPS * BATCH * 64 * 8; // 13.1 MB
    uint64_t* S1  = (uint64_t*)(ws + off); off += (size_t)T_STEPS * BATCH * 64 * 8; // 13.1 MB
    (void)off; (void)ws_size; (void)in_sizes; (void)n_in; (void)out_size;

    // 1) transpose + slab-pack weights (hb-contiguous)
    {
        long long tot0 = (long long)HID * IN_F;
        transpose_pack<<<(int)((tot0 + 255) / 256), 256, 0, stream>>>(W0, WT0, HID, IN_F);
        long long tot1 = (long long)HID * HID;
        transpose_pack<<<(int)((tot1 + 255) / 256), 256, 0, stream>>>(W1, WT1, HID, HID);
    }
    // 2) Poisson spike raster via threefry (partitionable, XOR readout)
    gen_spikes<<<(T_STEPS * BATCH) / 4, 256, 0, stream>>>(x, Sin);
    // 3) layer 0: 784 -> 4096, kc=264
    layer_fmac<KC_L0, IN_F, 16, HID, 4>
        <<<(HID / COLS) * BATCH, 256, 0, stream>>>(Sin, WT0, S0);
    // 4) layer 1: 4096 -> 4096, kc=280
    layer_fmac<KC_L1, HID, 64, HID, 4>
        <<<(HID / COLS) * BATCH, 256, 0, stream>>>(S0, WT1, S1);
    // 5) layer 2: 4096 -> 10, kc=280, spike counts
    layer_out<<<BATCH * 16 / 256, 256, 0, stream>>>(S1, W2, out);
}